// Round 1
// baseline (41087.219 us; speedup 1.0000x reference)
//
#include <hip/hip_runtime.h>

#define B_ 64
#define S_ 128
#define T_ 256
#define H_ 1024
#define IN_ 256  // 2*S

// ws layout (floats):
//   X    : [T][IN][B]  = 4,194,304   (per-step input, b-fastest)
//   hist : [T][H][B]   = 16,777,216  (h after step t, b-fastest)
//   c    : [H][B]      = 65,536
// fallback if ws too small: X lives in d_out (overwritten by finalize later)

__global__ __launch_bounds__(256) void build_X(const float* __restrict__ x,
                                               const float* __restrict__ y,
                                               float* __restrict__ X) {
  int flat = blockIdx.x * 256 + threadIdx.x;
  int b = flat & 63;
  int j = (flat >> 6) & 255;
  int t = flat >> 14;
  int s = j >> 1;
  float v;
  if ((j & 1) == 0) v = x[((size_t)b * S_ + s) * T_ + t];
  else              v = (t > 0) ? y[((size_t)b * S_ + s) * T_ + (t - 1)] : 0.0f;
  X[flat] = v;
}

__device__ __forceinline__ float sigm(float v) { return 1.0f / (1.0f + __expf(-v)); }

__global__ __launch_bounds__(256) void lstm_step(
    const float* __restrict__ X,
    const float* __restrict__ Wf, const float* __restrict__ bf,
    const float* __restrict__ Wi, const float* __restrict__ bi,
    const float* __restrict__ Wu, const float* __restrict__ bu,
    const float* __restrict__ Wo, const float* __restrict__ bo,
    float* __restrict__ hist, float* __restrict__ cst, int t) {
  __shared__ float sh[IN_ * B_];  // 64 KB staging chunk [k][b]
  const int tid = threadIdx.x;
  const int b = tid & 63;            // lane id = batch row
  const int cl = tid >> 6;           // wave id = which of 4 hcols
  const int hcol = blockIdx.x * 4 + cl;
  const int hc = __builtin_amdgcn_readfirstlane(hcol);  // wave-uniform -> s_loads for W

  float aF = bf[hc], aI = bi[hc], aU = bu[hc], aO = bo[hc];

  // ---- x part: K rows 0..255 of W, input X[t] ----
  {
    const float4* s4 = (const float4*)(X + (size_t)t * IN_ * B_);
    float4* d4 = (float4*)sh;
#pragma unroll
    for (int i = 0; i < 16; ++i) d4[tid + 256 * i] = s4[tid + 256 * i];
  }
  __syncthreads();
#pragma unroll 8
  for (int j = 0; j < IN_; ++j) {
    float hv = sh[j * 64 + b];
    aF = fmaf(hv, Wf[(size_t)j * H_ + hc], aF);
    aI = fmaf(hv, Wi[(size_t)j * H_ + hc], aI);
    aU = fmaf(hv, Wu[(size_t)j * H_ + hc], aU);
    aO = fmaf(hv, Wo[(size_t)j * H_ + hc], aO);
  }

  // ---- h part: K rows 256..1279, input h(t-1), 4 chunks of 256 ----
  if (t > 0) {
    const float* hp = hist + (size_t)(t - 1) * H_ * B_;
    for (int kc = 0; kc < 4; ++kc) {
      __syncthreads();
      const float4* s4 = (const float4*)(hp + (size_t)kc * 256 * B_);
      float4* d4 = (float4*)sh;
#pragma unroll
      for (int i = 0; i < 16; ++i) d4[tid + 256 * i] = s4[tid + 256 * i];
      __syncthreads();
      const float* wf = Wf + (size_t)(IN_ + kc * 256) * H_;
      const float* wi = Wi + (size_t)(IN_ + kc * 256) * H_;
      const float* wu = Wu + (size_t)(IN_ + kc * 256) * H_;
      const float* wo = Wo + (size_t)(IN_ + kc * 256) * H_;
#pragma unroll 8
      for (int kk = 0; kk < 256; ++kk) {
        float hv = sh[kk * 64 + b];
        aF = fmaf(hv, wf[(size_t)kk * H_ + hc], aF);
        aI = fmaf(hv, wi[(size_t)kk * H_ + hc], aI);
        aU = fmaf(hv, wu[(size_t)kk * H_ + hc], aU);
        aO = fmaf(hv, wo[(size_t)kk * H_ + hc], aO);
      }
    }
  }

  float fg = sigm(aF), ig = sigm(aI), og = sigm(aO);
  float ug = tanhf(aU);
  float cp = (t > 0) ? cst[hcol * B_ + b] : 0.0f;
  float cn = fmaf(cp, fg, ig * ug);
  cst[hcol * B_ + b] = cn;
  hist[((size_t)t * H_ + hcol) * B_ + b] = og * tanhf(cn);
}

// transpose hist [t][hc][b] -> out [b][hc][t]
__global__ __launch_bounds__(256) void finalize(const float* __restrict__ hist,
                                                float* __restrict__ out) {
  __shared__ float tile[64][65];
  int hc = blockIdx.x >> 2;
  int t0 = (blockIdx.x & 3) * 64;
  int tid = threadIdx.x;
  for (int idx = tid; idx < 4096; idx += 256) {
    int tl = idx >> 6, bl = idx & 63;
    tile[tl][bl] = hist[((size_t)(t0 + tl) * H_ + hc) * B_ + bl];
  }
  __syncthreads();
  for (int idx = tid; idx < 4096; idx += 256) {
    int bl = idx >> 6, tl = idx & 63;
    out[((size_t)bl * H_ + hc) * T_ + t0 + tl] = tile[tl][bl];
  }
}

__global__ __launch_bounds__(256) void write_c(const float* __restrict__ c,
                                               float* __restrict__ o) {
  int flat = blockIdx.x * 256 + threadIdx.x;  // flat = b*H + hc
  int bq = flat >> 10, hc = flat & 1023;
  o[flat] = c[hc * B_ + bq];
}

extern "C" void kernel_launch(void* const* d_in, const int* in_sizes, int n_in,
                              void* d_out, int out_size, void* d_ws, size_t ws_size,
                              hipStream_t stream) {
  const float* x  = (const float*)d_in[0];
  const float* y  = (const float*)d_in[2];
  const float* Wf = (const float*)d_in[3];  const float* bf = (const float*)d_in[4];
  const float* Wi = (const float*)d_in[5];  const float* bi = (const float*)d_in[6];
  const float* Wu = (const float*)d_in[7];  const float* bu = (const float*)d_in[8];
  const float* Wo = (const float*)d_in[9];  const float* bo = (const float*)d_in[10];
  float* out = (float*)d_out;
  float* ws  = (float*)d_ws;

  const size_t needX = (size_t)T_ * IN_ * B_;  // 4,194,304
  const size_t needH = (size_t)T_ * H_ * B_;   // 16,777,216
  const size_t needC = (size_t)H_ * B_;        // 65,536

  float *X, *hist, *cst;
  if (ws_size >= (needX + needH + needC) * sizeof(float)) {
    X = ws; hist = ws + needX; cst = hist + needH;
  } else {
    // park X in d_out (only needed before finalize overwrites it)
    X = out; hist = ws; cst = ws + needH;
  }

  build_X<<<(T_ * IN_ * B_) / 256, 256, 0, stream>>>(x, y, X);
  for (int t = 0; t < T_; ++t)
    lstm_step<<<256, 256, 0, stream>>>(X, Wf, bf, Wi, bi, Wu, bu, Wo, bo, hist, cst, t);
  finalize<<<H_ * (T_ / 64), 256, 0, stream>>>(hist, out);
  write_c<<<(B_ * H_) / 256, 256, 0, stream>>>(cst, out + (size_t)B_ * H_ * T_);
}

// Round 2
// 2404.567 us; speedup vs baseline: 17.0872x; 17.0872x over previous
//
#include <hip/hip_runtime.h>
#include <hip/hip_bf16.h>

#define B_ 64
#define T_ 256
#define H_ 1024
#define K_ 1280
#define NKK_ 40  // K / 32

typedef __attribute__((ext_vector_type(8))) short short8;
typedef __attribute__((ext_vector_type(4))) float float4_;

static __device__ __forceinline__ ushort f2bf(float v) {
  __hip_bfloat16 b = __float2bfloat16(v);
  return *reinterpret_cast<ushort*>(&b);
}
static __device__ __forceinline__ float sigm(float v) { return 1.0f / (1.0f + __expf(-v)); }

// Xall[t][b][j] bf16: j even = x[b][j/2][t], j odd = y[b][j/2][t-1] (0 at t=0)
__global__ __launch_bounds__(256) void build_X(const float* __restrict__ x,
                                               const float* __restrict__ y,
                                               ushort* __restrict__ Xall) {
  __shared__ float xl[128][33];
  __shared__ float yl[128][33];
  int b = blockIdx.x >> 3;
  int t0 = (blockIdx.x & 7) * 32;
  int tid = threadIdx.x;
  for (int it = 0; it < 16; ++it) {
    int idx = it * 256 + tid;
    int s = idx >> 5, tt = idx & 31;
    xl[s][tt] = x[((size_t)b * 128 + s) * T_ + t0 + tt];
    int ty = t0 + tt - 1;
    yl[s][tt] = (ty >= 0) ? y[((size_t)b * 128 + s) * T_ + ty] : 0.0f;
  }
  __syncthreads();
  for (int tt = 0; tt < 32; ++tt) {
    float v = (tid & 1) ? yl[tid >> 1][tt] : xl[tid >> 1][tt];
    Xall[((size_t)(t0 + tt) * B_ + b) * 256 + tid] = f2bf(v);
  }
}

// Bp[(nb*40+kk)*64 + l][8]: lane l of block nb supplies B[k=32kk+8*(l>>4)+j][localcol=l&15]
// localcol q -> gate g=q>>2, hcol-offset m=q&3; global gate col = g*1024 + 4nb+m
__global__ __launch_bounds__(256) void prep_weights(const float* __restrict__ Wf,
                                                    const float* __restrict__ Wi,
                                                    const float* __restrict__ Wu,
                                                    const float* __restrict__ Wo,
                                                    ushort* __restrict__ Bp) {
  int flat = blockIdx.x * 256 + threadIdx.x;  // (nb*40+kk)*64 + l
  int l = flat & 63;
  int g2 = flat >> 6;
  int kk = g2 % NKK_;
  int nb = g2 / NKK_;
  int q = l & 15, kg = l >> 4;
  int g = q >> 2, m = q & 3;
  const float* W = (g == 0) ? Wf : (g == 1) ? Wi : (g == 2) ? Wu : Wo;
  int col = nb * 4 + m;
  ushort tmp[8];
#pragma unroll
  for (int j = 0; j < 8; ++j) {
    int k = kk * 32 + kg * 8 + j;
    tmp[j] = f2bf(W[(size_t)k * H_ + col]);
  }
  *(short8*)(Bp + (size_t)flat * 8) = *(short8*)tmp;
}

__global__ __launch_bounds__(1024) void gate_step(
    const ushort* __restrict__ Xall, const ushort* __restrict__ Bp,
    const ushort* __restrict__ Hp, ushort* __restrict__ Hc,
    const float* __restrict__ bf, const float* __restrict__ bi,
    const float* __restrict__ bu, const float* __restrict__ bo,
    float* __restrict__ cst, float* __restrict__ out, int t) {
  __shared__ float gbuf[4][4][16][17];  // [kq][mt][row][col(q) pad]
  const int tid = threadIdx.x;
  const int w = tid >> 6, l = tid & 63;
  const int mt = w & 3, kq = w >> 2;
  const int ar = l & 15, kg = l >> 4;
  const int bA = mt * 16 + ar;  // batch row this lane supplies for A
  const int nb = blockIdx.x;

  float4_ acc = {0.f, 0.f, 0.f, 0.f};
  const ushort* xrow = Xall + ((size_t)t * B_ + bA) * 256 + kg * 8;
  const ushort* hrow = Hp + (size_t)bA * H_ + kg * 8;
  const ushort* bp = Bp + (((size_t)nb * NKK_) * 64 + l) * 8;
#pragma unroll
  for (int u = 0; u < 10; ++u) {
    int kk = kq * 10 + u;
    const ushort* ap = (kk < 8) ? (xrow + kk * 32) : (hrow + (kk - 8) * 32);
    short8 av = *(const short8*)ap;
    short8 bv = *(const short8*)(bp + (size_t)kk * 64 * 8);
    acc = __builtin_amdgcn_mfma_f32_16x16x32_bf16(av, bv, acc, 0, 0, 0);
  }
  {
    int rbase = (l >> 4) * 4, col = l & 15;
#pragma unroll
    for (int r = 0; r < 4; ++r) gbuf[kq][mt][rbase + r][col] = acc[r];
  }
  __syncthreads();
  if (tid < 256) {
    int bb = tid & 63, m = tid >> 6;
    int row = bb & 15, mtt = bb >> 4;
    float f = 0.f, i = 0.f, uu = 0.f, o = 0.f;
#pragma unroll
    for (int k2 = 0; k2 < 4; ++k2) {
      f += gbuf[k2][mtt][row][m];
      i += gbuf[k2][mtt][row][4 + m];
      uu += gbuf[k2][mtt][row][8 + m];
      o += gbuf[k2][mtt][row][12 + m];
    }
    int hcol = nb * 4 + m;
    f += bf[hcol]; i += bi[hcol]; uu += bu[hcol]; o += bo[hcol];
    float cp = (t > 0) ? cst[hcol * B_ + bb] : 0.0f;
    float cn = fmaf(cp, sigm(f), sigm(i) * tanhf(uu));
    cst[hcol * B_ + bb] = cn;
    float h = sigm(o) * tanhf(cn);
    out[((size_t)bb * H_ + hcol) * T_ + t] = h;
    Hc[(size_t)bb * H_ + hcol] = f2bf(h);
  }
}

__global__ __launch_bounds__(256) void write_c(const float* __restrict__ c,
                                               float* __restrict__ o) {
  int flat = blockIdx.x * 256 + threadIdx.x;  // flat = b*H + hc
  int bq = flat >> 10, hc = flat & 1023;
  o[flat] = c[hc * B_ + bq];
}

extern "C" void kernel_launch(void* const* d_in, const int* in_sizes, int n_in,
                              void* d_out, int out_size, void* d_ws, size_t ws_size,
                              hipStream_t stream) {
  const float* x  = (const float*)d_in[0];
  const float* y  = (const float*)d_in[2];
  const float* Wf = (const float*)d_in[3];  const float* bf = (const float*)d_in[4];
  const float* Wi = (const float*)d_in[5];  const float* bi = (const float*)d_in[6];
  const float* Wu = (const float*)d_in[7];  const float* bu = (const float*)d_in[8];
  const float* Wo = (const float*)d_in[9];  const float* bo = (const float*)d_in[10];
  float* out = (float*)d_out;

  // ws layout (bytes)
  char* p = (char*)d_ws;
  ushort* Bp   = (ushort*)p;                 p += (size_t)256 * NKK_ * 64 * 8 * 2;  // 10.5 MB
  ushort* Xall = (ushort*)p;                 p += (size_t)T_ * B_ * 256 * 2;        // 8.4 MB
  ushort* Hb   = (ushort*)p;                 p += (size_t)2 * B_ * H_ * 2;          // 256 KB
  float*  cst  = (float*)p;                  p += (size_t)H_ * B_ * 4;              // 256 KB

  prep_weights<<<(256 * NKK_ * 64) / 256, 256, 0, stream>>>(Wf, Wi, Wu, Wo, Bp);
  build_X<<<B_ * 8, 256, 0, stream>>>(x, y, Xall);
  hipMemsetAsync(Hb, 0, (size_t)2 * B_ * H_ * 2, stream);  // h0 = 0 (both buffers)

  for (int t = 0; t < T_; ++t) {
    const ushort* Hp = Hb + (size_t)(t & 1) * B_ * H_;
    ushort* Hc = (ushort*)(Hb + (size_t)((t + 1) & 1) * B_ * H_);
    gate_step<<<256, 1024, 0, stream>>>(Xall, Bp, Hp, Hc, bf, bi, bu, bo, cst, out, t);
  }
  write_c<<<(B_ * H_) / 256, 256, 0, stream>>>(cst, out + (size_t)B_ * H_ * T_);
}